// Round 14
// baseline (51.962 us; speedup 1.0000x reference)
//
#include <hip/hip_runtime.h>
#include <hip/hip_bf16.h>

// Problem constants
#define TT 2048
#define BB 4
#define CC 512
#define HH 16
#define KK 31
#define PP 15
#define MM (TT*BB)      // 8192 rows
#define NPAD 512

typedef __bf16 bf16x8 __attribute__((ext_vector_type(8)));
typedef float f32x4 __attribute__((ext_vector_type(4)));
typedef unsigned short ushort8 __attribute__((ext_vector_type(8)));

__device__ __forceinline__ float bf2f(unsigned short u) {
    return __uint_as_float(((unsigned int)u) << 16);
}
__device__ __forceinline__ unsigned short f2bf(float f) {
    unsigned int x = __float_as_uint(f);
    x += 0x7fffu + ((x >> 16) & 1u);
    return (unsigned short)(x >> 16);
}

// ---------------------------------------------------------------------------
// bf16 MFMA GEMM-NT with INLINE fp32->bf16 casting of operands.
// C[m,n] = sum_k A[m,k]*B[n,k] (+bias[n]); K fixed 512 (NT=8 x BK=64).
// 128x64 tile, 512 thr = 8 waves (4m x 2n), wave-tile 32x32 (R13 compute).
// B: ALWAYS reg-staged from fp32 (2x float4 -> cvt -> 1 ds_write_b128),
//    rows >= nvB are exec-masked to zero (Wl pad).
// A: AF32=1 -> reg-staged from fp32 (4x float4 -> 2 ds_write_b128)  [GEMM1: x]
//    AF32=0 -> global_load_lds bf16, pre-swizzled source            [GEMM2/3]
// Pipeline per iter kt (3-stage LDS, 72 KB -> 2 blocks/CU):
//   1. write LDS(kt+1) from regs   [compiler vmcnt wait; also retires
//      gloadA(kt): gloadA(kt) was issued BEFORE bregs(kt+1)]
//   2. load regs(kt+2)  (fp32)
//   3. lgkmcnt(0); [vmcnt(0) iff last]; s_barrier
//   4. gloadA(kt+2)                [after barrier: buf (kt-1)%3 is free]
//   5. compute(kt) on buf kt%3
// Buffer-reuse proofs: reg-write buf (kt-2)%3 at step1 is behind barrier kt-1;
// gloadA buf (kt-1)%3 at step4 is behind barrier kt. Swizzle slot^=(row&7):
// write-side for reg-staged, source-side for gload_lds.
// ---------------------------------------------------------------------------
#define GBM 128
#define GBN 64
#define GBK 64
#define KC  512
#define NT  8

#define PACK8(lo, hi, dst)                                                      \
    do { ushort8 o_;                                                            \
         o_[0] = f2bf((lo).x); o_[1] = f2bf((lo).y);                            \
         o_[2] = f2bf((lo).z); o_[3] = f2bf((lo).w);                            \
         o_[4] = f2bf((hi).x); o_[5] = f2bf((hi).y);                            \
         o_[6] = f2bf((hi).z); o_[7] = f2bf((hi).w);                            \
         *(ushort8*)(dst) = o_; } while (0)

#define LOADB(kt, d)                                                            \
    do { float4 z_ = make_float4(0.f, 0.f, 0.f, 0.f);                           \
         bLo[d] = z_; bHi[d] = z_;                                              \
         if (bok) { bLo[d] = *(const float4*)(gBf + (kt) * GBK);                \
                    bHi[d] = *(const float4*)(gBf + (kt) * GBK + 4); } } while (0)

#define WRITEB(kt, d) PACK8(bLo[d], bHi[d], &Bs[(kt) % 3][rB * 64 + psB * 8])

#define LOADA_F(kt, d)                                                          \
    do { _Pragma("unroll")                                                      \
         for (int j_ = 0; j_ < 2; ++j_) {                                       \
             aLo[d][j_] = *(const float4*)(gAf[j_] + (kt) * GBK);               \
             aHi[d][j_] = *(const float4*)(gAf[j_] + (kt) * GBK + 4);           \
         } } while (0)

#define WRITEA_F(kt, d)                                                         \
    do { _Pragma("unroll")                                                      \
         for (int j_ = 0; j_ < 2; ++j_)                                         \
             PACK8(aLo[d][j_], aHi[d][j_],                                      \
                   &As[(kt) % 3][rA[j_] * 64 + psA[j_] * 8]); } while (0)

#define STAGEA_G(kt, buf)                                                       \
    do { const int k0_ = (kt) * GBK;                                            \
         _Pragma("unroll")                                                      \
         for (int j_ = 0; j_ < 2; ++j_)                                         \
             __builtin_amdgcn_global_load_lds(                                  \
                 (const __attribute__((address_space(1))) void*)(gAg[j_] + k0_),\
                 (__attribute__((address_space(3))) void*)(&As[buf][0] + (j_ * 512 + wv * 64) * 8), \
                 16, 0, 0); } while (0)

template<int AF32, int OUT_BF16>
__global__ __launch_bounds__(512, 4) void gemm_nt_mfma(const void* __restrict__ Aptr,
                                                       const float* __restrict__ Bf,
                                                       int nvB,
                                                       const float* __restrict__ bias,
                                                       void* __restrict__ Cout,
                                                       int N, int nn) {
    __shared__ short As[3][GBM * GBK];   // 3 x 16 KB
    __shared__ short Bs[3][GBN * GBK];   // 3 x 8 KB

    const int tid = threadIdx.x;
    const int l   = tid & 63;
    const int wv  = tid >> 6;      // wave 0..7
    const int wr  = wv >> 1;       // wave row (0..3) -> 32 rows
    const int wc  = wv & 1;        // wave col (0..1) -> 32 cols

    // chunked XCD swizzle
    const int s  = (blockIdx.x & 7) * (gridDim.x >> 3) + (blockIdx.x >> 3);
    const int bm = (s / nn) * GBM;
    const int bn = (s % nn) * GBN;

    // ---- B reg-staging setup: 64 rows x 8 slots, 1 slot (8 f32) / thread ----
    const int rB  = tid >> 3;
    const int pB  = tid & 7;
    const int psB = pB ^ (rB & 7);           // write-side swizzle
    const float* gBf = Bf + (size_t)(bn + rB) * KC + pB * 8;
    const bool bok = (bn + rB) < nvB;
    float4 bLo[2], bHi[2];

    // ---- A staging setup ----
    int rA[2], psA[2];
    const float* gAf[2];                     // AF32 path
    const unsigned short* gAg[2];            // gload path
    #pragma unroll
    for (int j = 0; j < 2; ++j) {
        const int slot = j * 512 + tid;
        const int r = slot >> 3;
        const int p = slot & 7;
        rA[j] = r; psA[j] = p ^ (r & 7);
        gAf[j] = (const float*)Aptr + (size_t)(bm + r) * KC + p * 8;
        gAg[j] = (const unsigned short*)Aptr + (size_t)(bm + r) * KC + (p ^ (r & 7)) * 8;
    }
    float4 aLo[2][2], aHi[2][2];

    f32x4 acc[2][2] = {};

    const int lr = l & 15;
    const int ls = l >> 4;
    int offA[2][2], offB[2][2];
    #pragma unroll
    for (int mi = 0; mi < 2; ++mi) {
        const int r = wr * 32 + mi * 16 + lr;
        #pragma unroll
        for (int ks = 0; ks < 2; ++ks)
            offA[mi][ks] = r * 64 + (((ks * 4 + ls) ^ (r & 7)) * 8);
    }
    #pragma unroll
    for (int ni = 0; ni < 2; ++ni) {
        const int r = wc * 32 + ni * 16 + lr;
        #pragma unroll
        for (int ks = 0; ks < 2; ++ks)
            offB[ni][ks] = r * 64 + (((ks * 4 + ls) ^ (r & 7)) * 8);
    }

    // ---- prologue: tiles 0,1 ----
    LOADB(0, 0);
    if (AF32) LOADA_F(0, 0); else STAGEA_G(0, 0);
    LOADB(1, 1);
    if (AF32) LOADA_F(1, 1); else STAGEA_G(1, 1);
    WRITEB(0, 0);
    if (AF32) WRITEA_F(0, 0);

    #pragma unroll
    for (int kt = 0; kt < NT; ++kt) {
        // 1. write LDS tile kt+1 from regs (compiler inserts vmcnt wait)
        if (kt + 1 < NT) {
            WRITEB(kt + 1, (kt + 1) & 1);
            if (AF32) WRITEA_F(kt + 1, (kt + 1) & 1);
        }
        // 2. issue fp32 loads for tile kt+2
        if (kt + 2 < NT) {
            LOADB(kt + 2, (kt + 2) & 1);
            if (AF32) LOADA_F(kt + 2, (kt + 2) & 1);
        }
        // 3. fence + barrier (vmcnt NOT drained except final iter)
        asm volatile("s_waitcnt lgkmcnt(0)" ::: "memory");
        if (kt == NT - 1) asm volatile("s_waitcnt vmcnt(0)" ::: "memory");
        __builtin_amdgcn_s_barrier();
        asm volatile("" ::: "memory");
        // 4. async A stage for tile kt+2 (gload path only; post-barrier = safe)
        if (!AF32 && kt + 2 < NT) STAGEA_G(kt + 2, (kt + 2) % 3);

        // 5. compute tile kt
        const int cb = kt % 3;
        bf16x8 af[2][2], bfv[2][2];
        #pragma unroll
        for (int mi = 0; mi < 2; ++mi)
            #pragma unroll
            for (int ks = 0; ks < 2; ++ks)
                af[mi][ks] = *(const bf16x8*)&As[cb][offA[mi][ks]];
        #pragma unroll
        for (int ni = 0; ni < 2; ++ni)
            #pragma unroll
            for (int ks = 0; ks < 2; ++ks)
                bfv[ni][ks] = *(const bf16x8*)&Bs[cb][offB[ni][ks]];

        #pragma unroll
        for (int mi = 0; mi < 2; ++mi)
            #pragma unroll
            for (int ni = 0; ni < 2; ++ni)
                #pragma unroll
                for (int ks = 0; ks < 2; ++ks)
                    acc[mi][ni] = __builtin_amdgcn_mfma_f32_16x16x32_bf16(af[mi][ks], bfv[ni][ks], acc[mi][ni], 0, 0, 0);
    }

    // C/D layout (m89): col = lane&15, row = (lane>>4)*4 + j
    #pragma unroll
    for (int mi = 0; mi < 2; ++mi) {
        const int row0 = bm + wr * 32 + mi * 16 + ls * 4;
        #pragma unroll
        for (int ni = 0; ni < 2; ++ni) {
            const int col = bn + wc * 32 + ni * 16 + lr;
            const float bv = bias ? bias[col] : 0.0f;
            #pragma unroll
            for (int j = 0; j < 4; ++j) {
                const float v = acc[mi][ni][j] + bv;
                if (OUT_BF16)
                    ((unsigned short*)Cout)[(size_t)(row0 + j) * N + col] = f2bf(v);
                else
                    ((float*)Cout)[(size_t)(row0 + j) * N + col] = v;
            }
        }
    }
}

// ---------------------------------------------------------------------------
// Fused softmax + rolling dynamic conv (proven R9 version).
// Block = (4 consecutive t, one b), 64 threads (1 wave).
// ---------------------------------------------------------------------------
__global__ __launch_bounds__(64) void dynconv_fused(const unsigned short* __restrict__ hb,
                                                    const unsigned short* __restrict__ lgb,
                                                    unsigned short* __restrict__ cvb) {
    __shared__ float w_s[64][33];

    const int bid = blockIdx.x;
    const int u   = (bid & 7) * 256 + (bid >> 3);   // 2048 % 8 == 0, bijective
    const int tg  = u >> 2;
    const int b   = u & 3;
    const int t0  = tg * 4;
    const int tid = threadIdx.x;

    {
        const int dt = tid >> 4, hd = tid & 15;
        const unsigned short* lp = lgb + (size_t)((t0 + dt) * BB + b) * NPAD + hd * KK;
        float e[KK];
        float mx = -1e30f;
        #pragma unroll
        for (int k = 0; k < KK; ++k) { e[k] = bf2f(lp[k]); mx = fmaxf(mx, e[k]); }
        float sm = 0.f;
        #pragma unroll
        for (int k = 0; k < KK; ++k) { e[k] = __expf(e[k] - mx); sm += e[k]; }
        const float inv = 1.f / sm;
        #pragma unroll
        for (int k = 0; k < KK; ++k) w_s[tid][k] = e[k] * inv;
    }
    __syncthreads();

    const int c0 = tid * 8;
    const int hd = tid >> 2;
    float acc[4][8] = {};
    #pragma unroll
    for (int j = 0; j < 34; ++j) {
        const int tt = t0 - PP + j;
        if ((unsigned)tt >= TT) continue;
        const ushort8 hv = *(const ushort8*)&hb[(size_t)((tt * BB + b) * CC) + c0];
        float hf[8];
        #pragma unroll
        for (int cc = 0; cc < 8; ++cc) hf[cc] = bf2f(hv[cc]);
        #pragma unroll
        for (int dt = 0; dt < 4; ++dt) {
            const int k = j - dt;
            if (k < 0 || k >= KK) continue;
            const float wk = w_s[dt * 16 + hd][k];
            #pragma unroll
            for (int cc = 0; cc < 8; ++cc) acc[dt][cc] = fmaf(hf[cc], wk, acc[dt][cc]);
        }
    }
    #pragma unroll
    for (int dt = 0; dt < 4; ++dt) {
        ushort8 o;
        #pragma unroll
        for (int cc = 0; cc < 8; ++cc) o[cc] = f2bf(acc[dt][cc]);
        *(ushort8*)&cvb[(size_t)(((t0 + dt) * BB + b) * CC) + c0] = o;
    }
}

extern "C" void kernel_launch(void* const* d_in, const int* in_sizes, int n_in,
                              void* d_out, int out_size, void* d_ws, size_t ws_size,
                              hipStream_t stream) {
    const float* x  = (const float*)d_in[0];
    const float* W1 = (const float*)d_in[1];
    const float* b1 = (const float*)d_in[2];
    const float* Wl = (const float*)d_in[3];
    const float* W2 = (const float*)d_in[4];
    const float* b2 = (const float*)d_in[5];
    float* out = (float*)d_out;

    // workspace: only bf16 intermediates (24 MB)
    unsigned short* hb  = (unsigned short*)d_ws;             // 8 MB
    unsigned short* cvb = hb  + (size_t)MM * CC;             // 8 MB
    unsigned short* lgb = cvb + (size_t)MM * CC;             // 8 MB

    const int nblk = (MM / GBM) * (CC / GBN);   // 64 * 8 = 512

    // 1) h = x @ W1^T + b1        (A: x fp32 reg-staged; B: W1 fp32; bf16 out)
    gemm_nt_mfma<1, 1><<<nblk, 512, 0, stream>>>(x, W1, 512, b1, hb, CC, CC / GBN);
    // 2) logits = h @ Wl^T        (A: hb bf16 gload; B: Wl fp32, 496 valid rows)
    gemm_nt_mfma<0, 1><<<nblk, 512, 0, stream>>>(hb, Wl, HH * KK, nullptr, lgb, NPAD, NPAD / GBN);
    // 3+4) fused softmax + rolling dynamic conv (bf16 out)
    dynconv_fused<<<TT * BB / 4, 64, 0, stream>>>(hb, lgb, cvb);
    // 5) out = cv @ W2^T + b2     (A: cvb bf16 gload; B: W2 fp32; fp32 out)
    gemm_nt_mfma<0, 0><<<nblk, 512, 0, stream>>>(cvb, W2, 512, b2, out, CC, CC / GBN);
}